// Round 8
// baseline (969.036 us; speedup 1.0000x reference)
//
#include <hip/hip_runtime.h>
#include <hip/hip_bf16.h>

// ---------------------------------------------------------------------------
// DispEstimator pipeline, MFMA bf16 implicit-GEMM (R15).
// R15: convmfma_k commit phase split — between-barrier work is now PURE
// ds_write; the MODE transform runs inside the MFMA phase (one chunk after
// each dxi cluster), overlapping its VALU + load-latency with the matrix
// pipe. transpose/pre-conv pairs merged into single z=8 launches.
// ---------------------------------------------------------------------------

typedef __attribute__((ext_vector_type(8))) short short8;
typedef __attribute__((ext_vector_type(4))) float f32x4;
typedef _Float16 f16x8 __attribute__((ext_vector_type(8)));

__device__ __forceinline__ float s2f(short s) {
    unsigned int u = ((unsigned int)(unsigned short)s) << 16;
    float f; __builtin_memcpy(&f, &u, 4); return f;
}
__device__ __forceinline__ short f2s(float f) {
    __hip_bfloat16 h = __float2bfloat16(f);
    short s; __builtin_memcpy(&s, &h, 2); return s;
}
__device__ __forceinline__ short f2h(float f) {
    _Float16 h = (_Float16)f;
    short s; __builtin_memcpy(&s, &h, 2); return s;
}

__device__ __forceinline__ float gw(int j) {
    const float G[7] = {0.0366329f, 0.1112808f, 0.2167453f, 0.2706821f,
                        0.2167453f, 0.1112808f, 0.0366329f};
    return G[j];
}

// ---------------------------------------------------------------------------
// NCHW fp32 -> NHWC bf16 transpose, both feature maps. grid (1024, 8).
// z<4: feat1->T1 (b=z); z>=4: feat2->T2 (b=z-4).
// ---------------------------------------------------------------------------
__global__ __launch_bounds__(256) void transpose_k(const float* __restrict__ in1,
                                                   const float* __restrict__ in2,
                                                   short* __restrict__ out1,
                                                   short* __restrict__ out2)
{
    __shared__ float t[64][65];
    const int z = blockIdx.y;
    const float* in = (z < 4) ? in1 : in2;
    short* out = (z < 4) ? out1 : out2;
    const int b = z & 3;
    const int px0 = blockIdx.x * 64;
    #pragma unroll
    for (int k = 0; k < 16; ++k) {
        int idx = threadIdx.x + k * 256;
        int c = idx >> 6, x = idx & 63;
        t[c][x] = in[(size_t)(b * 64 + c) * 65536 + px0 + x];
    }
    __syncthreads();
    #pragma unroll
    for (int k = 0; k < 16; ++k) {
        int idx = threadIdx.x + k * 256;
        int px = idx >> 6, c = idx & 63;
        out[(size_t)(b * 65536 + px0 + px) * 64 + c] = f2s(t[c][px]);
    }
}

// ---------------------------------------------------------------------------
// Weight repack v2: [oc][cin][3][3] fp32 -> MFMA-native
// [o16][tap][cb][lane][8] bf16. Zero-padded.
// ---------------------------------------------------------------------------
__global__ __launch_bounds__(256) void repack2_k(const float* __restrict__ w,
                                                 short* __restrict__ o,
                                                 int cout, int cin, int CINP)
{
    int idx = blockIdx.x * 256 + threadIdx.x;
    int CB = CINP >> 5;
    int tot = cout * 9 * CINP;
    if (idx >= tot) return;
    int c8   = idx & 7;
    int lane = (idx >> 3) & 63;
    int rest = idx >> 9;          // ((o16*9+tap)*CB + cb)
    int cb   = rest % CB;
    int rest2 = rest / CB;
    int tap  = rest2 % 9;
    int o16  = rest2 / 9;
    int n16 = lane & 15, q = lane >> 4;
    int oc = o16 * 16 + n16;
    int ic = cb * 32 + q * 8 + c8;
    float v = (ic < cin) ? w[(size_t)(oc * cin + ic) * 9 + tap] : 0.f;
    o[idx] = f2s(v);
}

// ---------------------------------------------------------------------------
// MFMA implicit-GEMM 3x3 conv, NHWC bf16, zero pad = DIL, LDS row staging.
// Async split: issue(row n+1)->regs before MFMA(row n); the MODE transform
// runs INSIDE the MFMA phase (chunk per dxi) so its VALU hides under the
// matrix pipe; between-barrier commit is pure ds_write.
// MODE 0 plain; MODE 1 x*ka+kb + lrelu (xf=(ka,kb)); MODE 2 scale ic>=splitK
// by 1/(xf[b]/3211264+1e-6). Zeros outside image stay zero.
// zsplit/obDelta: blocks with blockIdx.z>=zsplit use srcB as primary source,
// OBASE+obDelta, b=b0+z-zsplit (merged dual-source launches, e.g. pre conv).
// grid:(XT*256 [/8-divisible, XCD-swizzled], cout/(16*NOC*WY), nb)
// ---------------------------------------------------------------------------
template<int DIL, int CINP, int WX, int WY, int NOC, int G, int MODE>
__global__ __launch_bounds__(256) void convmfma_k(
    const short* __restrict__ srcA, const short* __restrict__ srcB,
    int splitK, int csA, int csB,
    const short* __restrict__ wgt, const float* __restrict__ bias,
    short* __restrict__ out, int OSTR, int OBASE, int b0,
    const float* __restrict__ xf, int zsplit, int obDelta)
{
    static_assert(WX * WY == 4, "4 waves per block");
    constexpr int PXW = G * 16;
    constexpr int PXB = PXW * WX;
    constexpr int XT  = 256 / PXB;
    constexpr int CB  = CINP / 32;
    constexpr int UQ  = CINP / 8;       // 16B units per px
    constexpr int LUQ = (UQ == 16) ? 4 : ((UQ == 8) ? 3 : 2);
    static_assert(UQ == (1 << LUQ), "UQ must be 4/8/16");
    constexpr int UPX = UQ + 1;         // padded px stride (units)
    constexpr int WPX = PXB + 2 * DIL;  // staged px incl. halo
    constexpr int NTOT = WPX * UQ;
    constexpr int NIT  = (NTOT + 255) / 256;

    __shared__ __align__(16) short lds[WPX * UPX * 8];

    const int tid  = threadIdx.x;
    const int lane = tid & 63;
    const int wave = tid >> 6;
    const int q = lane >> 4, n16 = lane & 15;
    const int wx = wave % WX, wy = wave / WX;

    // bijective XCD swizzle (gridDim.x = XT*256, divisible by 8)
    constexpr int NX = XT * 256;
    const int bx = blockIdx.x;
    const int xs = (bx & 7) * (NX >> 3) + (bx >> 3);
    const int xt = xs % XT;
    const int y  = xs / XT;

    int zz = blockIdx.z;
    const short* s0 = srcA;
    int obase = OBASE;
    if (zz >= zsplit) { zz -= zsplit; s0 = srcB; obase += obDelta; }
    const int b  = b0 + zz;

    const int ocWaveBase = blockIdx.y * (16 * NOC * WY) + wy * (16 * NOC);
    const int o16base = ocWaveBase >> 4;
    const int x0 = xt * PXB + wx * PXW;
    const int gxbase = xt * PXB - DIL;

    const int bC = b * CINP;
    const float sc = (MODE == 2) ? 1.f / (xf[b] * (1.f / 3211264.f) + 1e-6f) : 0.f;

    short8 stg[NIT];

    // issue: global -> regs (no transform), in-flight across the compute phase
    auto issue = [&](int yy) {
        const int rowbase = (b * 256 + yy) * 256;
        #pragma unroll
        for (int it = 0; it < NIT; ++it) {
            const int i = tid + it * 256;
            short8 v = {0, 0, 0, 0, 0, 0, 0, 0};
            if (i < NTOT) {
                const int pxl = i >> LUQ;
                const int u   = i & (UQ - 1);
                const int gx  = gxbase + pxl;
                if ((unsigned)gx < 256u) {
                    const int ic = u * 8;
                    const short* p = (ic < splitK)
                        ? s0 + (size_t)(rowbase + gx) * csA + ic
                        : srcB + (size_t)(rowbase + gx) * csB + (ic - splitK);
                    v = *reinterpret_cast<const short8*>(p);
                }
            }
            stg[it] = v;
        }
    };

    // transform stg chunk [it0, it1) in registers (runs under the MFMA phase)
    auto transform = [&](int it0, int it1) {
        if (MODE == 0) return;
        #pragma unroll
        for (int it = 0; it < NIT; ++it) {
            if (it < it0 || it >= it1) continue;
            const int i = tid + it * 256;
            if (i >= NTOT) continue;
            const int pxl = i >> LUQ;
            const int u   = i & (UQ - 1);
            const int gx  = gxbase + pxl;
            if ((unsigned)gx >= 256u) continue;
            const int ic = u * 8;
            short8 v = stg[it];
            if (MODE == 1) {
                #pragma unroll
                for (int c = 0; c < 8; ++c) {
                    const float ka = xf[2 * (bC + ic + c)];
                    const float kb = xf[2 * (bC + ic + c) + 1];
                    float t = s2f(v[c]) * ka + kb;
                    t = fmaxf(t, 0.2f * t);
                    v[c] = f2s(t);
                }
                stg[it] = v;
            } else if (MODE == 2) {
                if (ic >= splitK) {
                    #pragma unroll
                    for (int c = 0; c < 8; ++c)
                        v[c] = f2s(s2f(v[c]) * sc);
                    stg[it] = v;
                }
            }
        }
    };

    // commit: pure LDS write (the only work between the barriers)
    auto commit = [&]() {
        #pragma unroll
        for (int it = 0; it < NIT; ++it) {
            const int i = tid + it * 256;
            if (i < NTOT) {
                const int pxl = i >> LUQ;
                const int u   = i & (UQ - 1);
                *reinterpret_cast<short8*>(&lds[(pxl * UPX + u) * 8]) = stg[it];
            }
        }
    };

    f32x4 acc[G][NOC];
    #pragma unroll
    for (int g = 0; g < G; ++g)
        #pragma unroll
        for (int t = 0; t < NOC; ++t)
            acc[g][t] = {0.f, 0.f, 0.f, 0.f};

    {   // prologue: issue + transform row for dyi=0
        const int yy0 = y - DIL;
        if ((unsigned)yy0 < 256u) { issue(yy0); transform(0, NIT); }
    }

    for (int dyi = 0; dyi < 3; ++dyi) {
        const int yy = y + (dyi - 1) * DIL;
        const bool rowok = ((unsigned)yy < 256u);   // block-uniform
        __syncthreads();                            // prev readers done
        if (rowok) commit();
        __syncthreads();                            // stage visible
        const int yn = y + dyi * DIL;
        const bool nextok = (dyi < 2) && ((unsigned)yn < 256u);
        if (nextok) issue(yn);                      // next row in flight

        if (rowok) {
            #pragma unroll
            for (int dxi = 0; dxi < 3; ++dxi) {
                const int tap = dyi * 3 + dxi;
                #pragma unroll
                for (int cb = 0; cb < CB; ++cb) {
                    short8 bfr[G];
                    #pragma unroll
                    for (int g = 0; g < G; ++g) {
                        const int pxl = wx * PXW + g * 16 + n16 + dxi * DIL;
                        bfr[g] = *reinterpret_cast<const short8*>(
                            &lds[(pxl * UPX + cb * 4 + q) * 8]);
                    }
                    #pragma unroll
                    for (int t = 0; t < NOC; ++t) {
                        short8 a = *reinterpret_cast<const short8*>(
                            wgt + ((((size_t)(o16base + t) * 9 + tap) * CB + cb) * 64 + lane) * 8);
                        #pragma unroll
                        for (int g = 0; g < G; ++g)
                            acc[g][t] = __builtin_amdgcn_mfma_f32_16x16x32_bf16(
                                a, bfr[g], acc[g][t], 0, 0, 0);
                    }
                }
                if (nextok) transform((dxi * NIT) / 3, ((dxi + 1) * NIT) / 3);
            }
        } else if (nextok) {
            transform(0, NIT);
        }
    }

    #pragma unroll
    for (int g = 0; g < G; ++g) {
        const size_t px_lin = (size_t)(b * 256 + y) * 256 + x0 + g * 16 + n16;
        #pragma unroll
        for (int t = 0; t < NOC; ++t) {
            const int oc = ocWaveBase + t * 16 + q * 4;
            f32x4 v = acc[g][t];
            if (bias) {
                v.x += bias[oc];     v.y += bias[oc + 1];
                v.z += bias[oc + 2]; v.w += bias[oc + 3];
            }
            ushort4 pk;
            pk.x = (unsigned short)f2s(v.x);
            pk.y = (unsigned short)f2s(v.y);
            pk.z = (unsigned short)f2s(v.z);
            pk.w = (unsigned short)f2s(v.w);
            *reinterpret_cast<ushort4*>(out + px_lin * OSTR + obase + oc) = pk;
        }
    }
}

// ---------------------------------------------------------------------------
// Instance-norm partial sums, NHWC. grid (128 slices, B), block 256.
// ---------------------------------------------------------------------------
__global__ __launch_bounds__(256) void in_stats_nhwc_k(const short* __restrict__ x,
                                                       float* __restrict__ sums,
                                                       int C, int lC)
{
    __shared__ float ls[256], lss[256];
    const int tid = threadIdx.x;
    const int b = blockIdx.y;
    const int c = tid & (C - 1);
    const int sub = tid >> lC;
    const int tpc = 256 >> lC;
    const int px0 = blockIdx.x * 512;
    float s = 0.f, ss = 0.f;
    for (int p = sub; p < 512; p += tpc) {
        float v = s2f(x[(size_t)(b * 65536 + px0 + p) * C + c]);
        s += v; ss += v * v;
    }
    ls[tid] = s; lss[tid] = ss;
    __syncthreads();
    if (tid < C) {
        float s0 = ls[tid], ss0 = lss[tid];
        for (int j = 1; j < tpc; ++j) { s0 += ls[tid + j * C]; ss0 += lss[tid + j * C]; }
        atomicAdd(sums + 2 * (b * C + tid), s0);
        atomicAdd(sums + 2 * (b * C + tid) + 1, ss0);
    }
}

// Emits (ka, kb): apply = x*ka + kb (ka = rsqrt*gamma, kb = beta - m*ka).
__global__ __launch_bounds__(256) void in_finalize_k(const float* __restrict__ sums,
                                                     float* __restrict__ stats,
                                                     const float* __restrict__ gamma,
                                                     const float* __restrict__ beta,
                                                     int lC, int n)
{
    int i = blockIdx.x * 256 + threadIdx.x;
    if (i >= n) return;
    int c = i & ((1 << lC) - 1);
    float m = sums[2 * i] * (1.f / 65536.f);
    float var = sums[2 * i + 1] * (1.f / 65536.f) - m * m;
    if (var < 0.f) var = 0.f;
    float ka = rsqrtf(var + 1e-5f) * gamma[c];
    stats[2 * i] = ka;
    stats[2 * i + 1] = beta[c] - m * ka;
}

// ---------------------------------------------------------------------------
// Separable 7x7 gaussian blur of f1 (A ch 0-63, replicate edges) -> fp16
// planes, group-major: B1[((g*4+b)<<16 | px)*8 + c]. grid (256*8, B).
// ---------------------------------------------------------------------------
__global__ __launch_bounds__(256) void blur_k(const short* __restrict__ A,
                                              short* __restrict__ B1)
{
    __shared__ __align__(16) short raw[484 * 8];    // 22x22 halo, 7.7 KB
    __shared__ __align__(16) float hb[352 * 12];    // 22 rows x 16 cols, 16.9 KB

    const int tid  = threadIdx.x;
    const int tile = blockIdx.x >> 3;
    const int g    = blockIdx.x & 7;
    const int c0   = g * 8;
    const int tx = (tile & 15) << 4;
    const int ty = (tile >> 4) << 4;
    const int b  = blockIdx.y;

    #pragma unroll
    for (int it = 0; it < 2; ++it) {
        int i = tid + it * 256;
        if (i < 484) {
            int y = i / 22, x = i - y * 22;
            int gy = ty + y - 3, gx = tx + x - 3;
            gy = gy < 0 ? 0 : (gy > 255 ? 255 : gy);
            gx = gx < 0 ? 0 : (gx > 255 ? 255 : gx);
            *reinterpret_cast<short8*>(&raw[i * 8]) =
                *reinterpret_cast<const short8*>(
                    &A[(size_t)((b << 16) + (gy << 8) + gx) * 128 + c0]);
        }
    }
    __syncthreads();

    #pragma unroll
    for (int it = 0; it < 2; ++it) {
        int i = tid + it * 256;
        if (i < 352) {                       // 22 rows x 16 core cols
            int r = i >> 4, cc = i & 15;
            float s[8];
            #pragma unroll
            for (int c = 0; c < 8; ++c) s[c] = 0.f;
            #pragma unroll
            for (int j = 0; j < 7; ++j) {
                short8 v = *reinterpret_cast<const short8*>(&raw[(r * 22 + cc + j) * 8]);
                float w = gw(j);
                #pragma unroll
                for (int c = 0; c < 8; ++c) s[c] += w * s2f(v[c]);
            }
            #pragma unroll
            for (int c = 0; c < 8; ++c) hb[i * 12 + c] = s[c];
        }
    }
    __syncthreads();

    const int py = tid >> 4, px = tid & 15;
    float s[8];
    #pragma unroll
    for (int c = 0; c < 8; ++c) s[c] = 0.f;
    #pragma unroll
    for (int j = 0; j < 7; ++j) {
        const float* hp = &hb[((py + j) * 16 + px) * 12];
        float w = gw(j);
        #pragma unroll
        for (int c = 0; c < 8; ++c) s[c] += w * hp[c];
    }
    short8 ov;
    #pragma unroll
    for (int c = 0; c < 8; ++c) ov[c] = f2h(s[c]);
    *reinterpret_cast<short8*>(
        &B1[(size_t)(((g * 4 + b) << 16) + ((ty + py) << 8) + tx + px) * 8]) = ov;
}

// ---------------------------------------------------------------------------
// Local correlation from pre-blurred f1 (fp16 planes) + f2 (A ch 64-127).
// fp16 LDS tiles (row stride 24 cells), double-buffered, v_dot2_f32_f16 SSD.
// Writes UN-normalized lc (e1 staging applies the scale).
// ---------------------------------------------------------------------------
__global__ __launch_bounds__(256, 2) void corr2_k(const short* __restrict__ A,
                                                  const short* __restrict__ B1,
                                                  short* __restrict__ lcPad,
                                                  float* __restrict__ lcsum)
{
    __shared__ __align__(16) short blh[2][22 * 24 * 8];  // 16.5 KB
    __shared__ float red[4];

    const int tid = threadIdx.x;
    const int tx = (blockIdx.x & 15) << 4;
    const int ty = (blockIdx.x >> 4) << 4;
    const int b  = blockIdx.y;
    const int py = tid >> 4, px = tid & 15;

    // Staging descriptors for cells tid and tid+256 (halo +-3).
    int y0 = tid / 22, x0c = tid - y0 * 22;
    int gy0 = ty + y0 - 3, gx0 = tx + x0c - 3;
    const bool ok0 = (gy0 >= 0 && gy0 < 256 && gx0 >= 0 && gx0 < 256);
    gy0 = gy0 < 0 ? 0 : (gy0 > 255 ? 255 : gy0);
    gx0 = gx0 < 0 ? 0 : (gx0 > 255 ? 255 : gx0);
    const int off0 = (gy0 << 8) + gx0;
    const int lc0 = y0 * 24 + x0c;

    const int c1 = tid + 256;
    int y1 = c1 / 22, x1c = c1 - y1 * 22;
    int gy1 = ty + y1 - 3, gx1 = tx + x1c - 3;
    const bool ok1 = (gy1 >= 0 && gy1 < 256 && gx1 >= 0 && gx1 < 256);
    gy1 = gy1 < 0 ? 0 : (gy1 > 255 ? 255 : gy1);
    gx1 = gx1 < 0 ? 0 : (gx1 > 255 ? 255 : gx1);
    const int off1 = (gy1 << 8) + gx1;
    const int lc1 = y1 * 24 + x1c;
    const bool has1 = (c1 < 484);

    const short* f2p = &A[(size_t)((b << 16) + ((ty + py) << 8) + tx + px) * 128 + 64];

    float acc[49];
    #pragma unroll
    for (int k = 0; k < 49; ++k) acc[k] = 0.f;

    for (int g = 0; g < 8; ++g) {
        const size_t plane = (size_t)(g * 4 + b) << 16;
        short* buf = blh[g & 1];

        {
            short8 v = *reinterpret_cast<const short8*>(&B1[(plane + off0) * 8]);
            if (!ok0) v = v ^ v;
            *reinterpret_cast<short8*>(&buf[lc0 * 8]) = v;
            if (has1) {
                short8 w = *reinterpret_cast<const short8*>(&B1[(plane + off1) * 8]);
                if (!ok1) w = w ^ w;
                *reinterpret_cast<short8*>(&buf[lc1 * 8]) = w;
            }
        }

        short8 f2raw = *reinterpret_cast<const short8*>(f2p + g * 8);
        f16x8 f2v;
        #pragma unroll
        for (int c = 0; c < 8; ++c) f2v[c] = (_Float16)s2f(f2raw[c]);

        __syncthreads();

        const short* blp = &buf[(py * 24 + px) * 8];
        #pragma unroll
        for (int i = 0; i < 7; ++i)
            #pragma unroll
            for (int j = 0; j < 7; ++j) {
                f16x8 bv = *reinterpret_cast<const f16x8*>(blp + (i * 24 + j) * 8);
                f16x8 d = f2v - bv;
                float a = acc[i * 7 + j];
#if __has_builtin(__builtin_amdgcn_fdot2)
                a = __builtin_amdgcn_fdot2(__builtin_shufflevector(d, d, 0, 1),
                                           __builtin_shufflevector(d, d, 0, 1), a, false);
                a = __builtin_amdgcn_fdot2(__builtin_shufflevector(d, d, 2, 3),
                                           __builtin_shufflevector(d, d, 2, 3), a, false);
                a = __builtin_amdgcn_fdot2(__builtin_shufflevector(d, d, 4, 5),
                                           __builtin_shufflevector(d, d, 4, 5), a, false);
                a = __builtin_amdgcn_fdot2(__builtin_shufflevector(d, d, 6, 7),
                                           __builtin_shufflevector(d, d, 6, 7), a, false);
#else
                #pragma unroll
                for (int c = 0; c < 8; ++c) {
                    float df = (float)d[c];
                    a += df * df;
                }
#endif
                acc[i * 7 + j] = a;
            }
        __syncthreads();
    }

    const size_t base = (size_t)((b << 16) + ((ty + py) << 8) + tx + px) * 64;
    float tot = 0.f;
    #pragma unroll
    for (int k = 0; k < 49; ++k) {
        float m = acc[k] * (1.f / 64.f);
        lcPad[base + k] = f2s(m);
        tot += m;
    }
    #pragma unroll
    for (int k = 49; k < 64; ++k) lcPad[base + k] = 0;

    for (int o = 32; o; o >>= 1) tot += __shfl_down(tot, o);
    if ((tid & 63) == 0) red[tid >> 6] = tot;
    __syncthreads();
    if (tid == 0) atomicAdd(lcsum + b, red[0] + red[1] + red[2] + red[3]);
}

// ---------------------------------------------------------------------------
// Head conv: applies e3's IN+lrelu (ka,kb table) inline, NHWC bf16 [b,px,16]
// -> NCHW fp32 planes [b*2+oc][px].
// ---------------------------------------------------------------------------
__global__ __launch_bounds__(256) void head_k(const short* __restrict__ e3,
                                              const float* __restrict__ w,
                                              const float* __restrict__ bias,
                                              const float* __restrict__ kst,
                                              float* __restrict__ hd)
{
    int pix = blockIdx.x * 256 + threadIdx.x;
    int b = pix >> 16, rem = pix & 65535;
    int y = rem >> 8, x = rem & 255;
    float ka[16], kb[16];
    #pragma unroll
    for (int ic = 0; ic < 16; ++ic) {
        ka[ic] = kst[2 * (b * 16 + ic)];
        kb[ic] = kst[2 * (b * 16 + ic) + 1];
    }
    float a0 = bias[0], a1 = bias[1];
    #pragma unroll
    for (int tap = 0; tap < 9; ++tap) {
        int yy = y + tap / 3 - 1, xx = x + tap % 3 - 1;
        if ((unsigned)yy >= 256u || (unsigned)xx >= 256u) continue;
        const short* p = e3 + (size_t)((b << 16) + (yy << 8) + xx) * 16;
        #pragma unroll
        for (int ic = 0; ic < 16; ++ic) {
            float v = s2f(p[ic]) * ka[ic] + kb[ic];
            v = fmaxf(v, 0.2f * v);
            a0 += v * w[ic * 9 + tap];
            a1 += v * w[(16 + ic) * 9 + tap];
        }
    }
    hd[(size_t)(b * 2) * 65536 + rem]     = a0;
    hd[(size_t)(b * 2 + 1) * 65536 + rem] = a1;
}

// ---------------------------------------------------------------------------
// Final separable 7-tap gaussian blur (replicate edges), fp32 planes.
// ---------------------------------------------------------------------------
__global__ __launch_bounds__(256) void blur7f_k(const float* __restrict__ in,
                                                float* __restrict__ out)
{
    __shared__ float raw[22 * 22];
    __shared__ float hb[22 * 16];
    const int tid = threadIdx.x;
    const int tx = (blockIdx.x & 15) << 4;
    const int ty = (blockIdx.x >> 4) << 4;
    const size_t ch = ((size_t)blockIdx.y) << 16;
    const int py = tid >> 4, px = tid & 15;

    for (int i = tid; i < 484; i += 256) {
        int y = i / 22, x = i - y * 22;
        int gy = ty + y - 3, gx = tx + x - 3;
        gy = gy < 0 ? 0 : (gy > 255 ? 255 : gy);
        gx = gx < 0 ? 0 : (gx > 255 ? 255 : gx);
        raw[i] = in[ch + (gy << 8) + gx];
    }
    __syncthreads();
    for (int i = tid; i < 352; i += 256) {
        int r = i >> 4, cc = i & 15;
        float s = 0.f;
        #pragma unroll
        for (int j = 0; j < 7; ++j) s += gw(j) * raw[r * 22 + cc + j];
        hb[i] = s;
    }
    __syncthreads();
    float s = 0.f;
    #pragma unroll
    for (int j = 0; j < 7; ++j) s += gw(j) * hb[(py + j) * 16 + px];
    out[ch + ((ty + py) << 8) + tx + px] = s;
}

// ---------------------------------------------------------------------------
extern "C" void kernel_launch(void* const* d_in, const int* in_sizes, int n_in,
                              void* d_out, int out_size, void* d_ws, size_t ws_size,
                              hipStream_t stream)
{
    const float* feat1  = (const float*)d_in[0];
    const float* feat2  = (const float*)d_in[1];
    const float* pre_w  = (const float*)d_in[2];
    const float* pre_b  = (const float*)d_in[3];
    const float* fc1_w  = (const float*)d_in[4];
    const float* fc1_g  = (const float*)d_in[5];
    const float* fc1_be = (const float*)d_in[6];
    const float* fc2_w  = (const float*)d_in[7];
    const float* fc2_b  = (const float*)d_in[8];
    const float* e1_w   = (const float*)d_in[9];
    const float* e1_g   = (const float*)d_in[10];
    const float* e1_be  = (const float*)d_in[11];
    const float* e2_w   = (const float*)d_in[12];
    const float* e2_g   = (const float*)d_in[13];
    const float* e2_be  = (const float*)d_in[14];
    const float* e3_w   = (const float*)d_in[15];
    const float* e3_g   = (const float*)d_in[16];
    const float* e3_be  = (const float*)d_in[17];
    const float* head_w = (const float*)d_in[18];
    const float* head_b = (const float*)d_in[19];
    float* out = (float*)d_out;

    const size_t NEED = 152000000;
    if (ws_size < NEED) return;

    char* ws = (char*)d_ws;
    short* T1      = (short*)(ws);
    short* T2      = (short*)(ws + 33554432);
    short* lcPad   = (short*)(ws);
    short* B1h     = (short*)(ws + 33554432);   // blurred f1, fp16 group-major
    short* featBuf = (short*)(ws + 33554432);
    short* A       = (short*)(ws + 67108864);
    short* FC1o    = (short*)(ws + 83886080);
    short* E1o     = (short*)(ws + 67108864);
    short* E2o     = (short*)(ws + 100663296);
    short* E3o     = (short*)(ws + 117440512);
    float* HD      = (float*)(ws + 125829120);
    short* preW    = (short*)(ws + 150994944);
    short* fc1W    = (short*)(ws + 151068672);
    short* fc2W    = (short*)(ws + 151363584);
    short* e1W     = (short*)(ws + 151511040);
    short* e2W     = (short*)(ws + 151658496);
    short* e3W     = (short*)(ws + 151695360);
    float* sums0   = (float*)(ws + 151704576);
    float* sums1   = (float*)(ws + 151708672);
    float* sums2   = (float*)(ws + 151712768);
    float* sums3   = (float*)(ws + 151716864);
    float* stats0  = (float*)(ws + 151720960);
    float* stats1  = (float*)(ws + 151725056);
    float* stats2  = (float*)(ws + 151729152);
    float* stats3  = (float*)(ws + 151733248);
    float* LS      = (float*)(ws + 151737344);

    hipMemsetAsync(ws + 151704576, 0, 32784, stream);

    // both transposes in one launch (z<4: feat1->T1, z>=4: feat2->T2)
    transpose_k<<<dim3(1024, 8), 256, 0, stream>>>(feat1, feat2, T1, T2);

    repack2_k<<<144, 256, 0, stream>>>(pre_w, preW, 64, 64, 64);
    repack2_k<<<576, 256, 0, stream>>>(fc1_w, fc1W, 128, 128, 128);
    repack2_k<<<288, 256, 0, stream>>>(fc2_w, fc2W, 64, 128, 128);
    repack2_k<<<288, 256, 0, stream>>>(e1_w, e1W, 64, 113, 128);
    repack2_k<<<72, 256, 0, stream>>>(e2_w, e2W, 32, 64, 64);
    repack2_k<<<18, 256, 0, stream>>>(e3_w, e3W, 16, 32, 32);

    // pre conv (cout=64): both feature maps in one z=8 launch
    // (z<4: T1 -> A ch0-63; z>=4: T2 -> A ch64-127 via zsplit/obDelta)
    convmfma_k<1, 64, 2, 2, 2, 4, 0><<<dim3(512, 1, 8), 256, 0, stream>>>(
        T1, T2, 64, 64, 64, preW, pre_b, A, 128, 0, 0, nullptr, 4, 64);

    // blur f1 -> fp16 planes, then local correlation (un-normalized lc)
    blur_k<<<dim3(2048, 4), 256, 0, stream>>>(A, B1h);
    corr2_k<<<dim3(256, 4), 256, 0, stream>>>(A, B1h, lcPad, LS);

    // fc1 (cout=128): batch-phased (FC1o[b] aliases A[b+1]); G=2 -> 1024
    // blocks per launch (4 blocks/CU)
    for (int b = 3; b >= 0; --b)
        convmfma_k<1, 128, 2, 2, 4, 2, 0><<<dim3(1024, 1, 1), 256, 0, stream>>>(
            A, A, 128, 128, 128, fc1W, nullptr, FC1o, 128, 0, b, nullptr, 100, 0);
    in_stats_nhwc_k<<<dim3(128, 4), 256, 0, stream>>>(FC1o, sums0, 128, 7);
    in_finalize_k<<<2, 256, 0, stream>>>(sums0, stats0, fc1_g, fc1_be, 7, 512);

    // fc2 (cout=64): stages FC1o with IN+lrelu (MODE1, stats0)
    convmfma_k<1, 128, 2, 2, 2, 4, 1><<<dim3(512, 1, 4), 256, 0, stream>>>(
        FC1o, FC1o, 128, 128, 128, fc2W, fc2_b, featBuf, 64, 0, 0, stats0, 100, 0);

    // e1 (cout=64): concat(featBuf, lcPad); lc scale applied in staging (MODE2)
    convmfma_k<1, 128, 2, 2, 2, 4, 2><<<dim3(512, 1, 4), 256, 0, stream>>>(
        featBuf, lcPad, 64, 64, 64, e1W, nullptr, E1o, 64, 0, 0, LS, 100, 0);
    in_stats_nhwc_k<<<dim3(128, 4), 256, 0, stream>>>(E1o, sums1, 64, 6);
    in_finalize_k<<<1, 256, 0, stream>>>(sums1, stats1, e1_g, e1_be, 6, 256);

    // e2 (cout=32): dil=2; stages E1o with IN+lrelu (stats1)
    convmfma_k<2, 64, 2, 2, 1, 4, 1><<<dim3(512, 1, 4), 256, 0, stream>>>(
        E1o, E1o, 64, 64, 64, e2W, nullptr, E2o, 32, 0, 0, stats1, 100, 0);
    in_stats_nhwc_k<<<dim3(128, 4), 256, 0, stream>>>(E2o, sums2, 32, 5);
    in_finalize_k<<<1, 256, 0, stream>>>(sums2, stats2, e2_g, e2_be, 5, 128);

    // e3 (cout=16): dil=4; stages E2o with IN+lrelu (stats2)
    convmfma_k<4, 32, 4, 1, 1, 4, 1><<<dim3(256, 1, 4), 256, 0, stream>>>(
        E2o, E2o, 32, 32, 32, e3W, nullptr, E3o, 16, 0, 0, stats2, 100, 0);
    in_stats_nhwc_k<<<dim3(128, 4), 256, 0, stream>>>(E3o, sums3, 16, 4);
    in_finalize_k<<<1, 256, 0, stream>>>(sums3, stats3, e3_g, e3_be, 4, 64);

    // head applies e3's IN+lrelu inline
    head_k<<<1024, 256, 0, stream>>>(E3o, head_w, head_b, stats3, HD);
    blur7f_k<<<dim3(256, 8), 256, 0, stream>>>(HD, out);
}

// Round 9
// 897.627 us; speedup vs baseline: 1.0796x; 1.0796x over previous
//
#include <hip/hip_runtime.h>
#include <hip/hip_bf16.h>

// ---------------------------------------------------------------------------
// DispEstimator pipeline, MFMA bf16 implicit-GEMM (R16).
// R16: revert R15's transform-split AND R14's register prefetch (both cost
// VGPR -> occupancy with no gain: 64r/40% = 96r/21% in time). Synchronous
// R13-style staging (load+transform+ds_write between barriers, VGPR ~64) +
// SMALLER TILES for residency: fc2/e1 G=2 (17.9KB LDS, 8 blocks/CU vs 4),
// e2 G=2 (9.8KB), e3 G=2/WX=4 (10.9KB, grid 512 vs 256). Barrier/latency
// stalls (60% of cycles) overlap across blocks instead of within waves.
// ---------------------------------------------------------------------------

typedef __attribute__((ext_vector_type(8))) short short8;
typedef __attribute__((ext_vector_type(4))) float f32x4;
typedef _Float16 f16x8 __attribute__((ext_vector_type(8)));

__device__ __forceinline__ float s2f(short s) {
    unsigned int u = ((unsigned int)(unsigned short)s) << 16;
    float f; __builtin_memcpy(&f, &u, 4); return f;
}
__device__ __forceinline__ short f2s(float f) {
    __hip_bfloat16 h = __float2bfloat16(f);
    short s; __builtin_memcpy(&s, &h, 2); return s;
}
__device__ __forceinline__ short f2h(float f) {
    _Float16 h = (_Float16)f;
    short s; __builtin_memcpy(&s, &h, 2); return s;
}

__device__ __forceinline__ float gw(int j) {
    const float G[7] = {0.0366329f, 0.1112808f, 0.2167453f, 0.2706821f,
                        0.2167453f, 0.1112808f, 0.0366329f};
    return G[j];
}

// ---------------------------------------------------------------------------
// NCHW fp32 -> NHWC bf16 transpose, both feature maps. grid (1024, 8).
// z<4: feat1->T1 (b=z); z>=4: feat2->T2 (b=z-4).
// ---------------------------------------------------------------------------
__global__ __launch_bounds__(256) void transpose_k(const float* __restrict__ in1,
                                                   const float* __restrict__ in2,
                                                   short* __restrict__ out1,
                                                   short* __restrict__ out2)
{
    __shared__ float t[64][65];
    const int z = blockIdx.y;
    const float* in = (z < 4) ? in1 : in2;
    short* out = (z < 4) ? out1 : out2;
    const int b = z & 3;
    const int px0 = blockIdx.x * 64;
    #pragma unroll
    for (int k = 0; k < 16; ++k) {
        int idx = threadIdx.x + k * 256;
        int c = idx >> 6, x = idx & 63;
        t[c][x] = in[(size_t)(b * 64 + c) * 65536 + px0 + x];
    }
    __syncthreads();
    #pragma unroll
    for (int k = 0; k < 16; ++k) {
        int idx = threadIdx.x + k * 256;
        int px = idx >> 6, c = idx & 63;
        out[(size_t)(b * 65536 + px0 + px) * 64 + c] = f2s(t[c][px]);
    }
}

// ---------------------------------------------------------------------------
// Weight repack v2: [oc][cin][3][3] fp32 -> MFMA-native
// [o16][tap][cb][lane][8] bf16. Zero-padded.
// ---------------------------------------------------------------------------
__global__ __launch_bounds__(256) void repack2_k(const float* __restrict__ w,
                                                 short* __restrict__ o,
                                                 int cout, int cin, int CINP)
{
    int idx = blockIdx.x * 256 + threadIdx.x;
    int CB = CINP >> 5;
    int tot = cout * 9 * CINP;
    if (idx >= tot) return;
    int c8   = idx & 7;
    int lane = (idx >> 3) & 63;
    int rest = idx >> 9;          // ((o16*9+tap)*CB + cb)
    int cb   = rest % CB;
    int rest2 = rest / CB;
    int tap  = rest2 % 9;
    int o16  = rest2 / 9;
    int n16 = lane & 15, q = lane >> 4;
    int oc = o16 * 16 + n16;
    int ic = cb * 32 + q * 8 + c8;
    float v = (ic < cin) ? w[(size_t)(oc * cin + ic) * 9 + tap] : 0.f;
    o[idx] = f2s(v);
}

// ---------------------------------------------------------------------------
// MFMA implicit-GEMM 3x3 conv, NHWC bf16, zero pad = DIL, LDS row staging
// (synchronous: load + MODE transform + ds_write between barriers — the
// VGPR-cheap structure; wave TLP across 8 resident blocks hides latency).
// MODE 0 plain; MODE 1 x*ka+kb + lrelu (xf=(ka,kb)); MODE 2 scale ic>=splitK
// by 1/(xf[b]/3211264+1e-6). Zeros outside image stay zero.
// zsplit/obDelta: blocks with blockIdx.z>=zsplit use srcB as primary source,
// OBASE+obDelta, b=b0+z-zsplit (merged dual-source launches, e.g. pre conv).
// grid:(XT*256 [/8-divisible, XCD-swizzled], cout/(16*NOC*WY), nb)
// ---------------------------------------------------------------------------
template<int DIL, int CINP, int WX, int WY, int NOC, int G, int MODE>
__global__ __launch_bounds__(256) void convmfma_k(
    const short* __restrict__ srcA, const short* __restrict__ srcB,
    int splitK, int csA, int csB,
    const short* __restrict__ wgt, const float* __restrict__ bias,
    short* __restrict__ out, int OSTR, int OBASE, int b0,
    const float* __restrict__ xf, int zsplit, int obDelta)
{
    static_assert(WX * WY == 4, "4 waves per block");
    constexpr int PXW = G * 16;
    constexpr int PXB = PXW * WX;
    constexpr int XT  = 256 / PXB;
    constexpr int CB  = CINP / 32;
    constexpr int UQ  = CINP / 8;       // 16B units per px
    constexpr int UPX = UQ + 1;         // padded px stride (units)
    constexpr int WPX = PXB + 2 * DIL;  // staged px incl. halo

    __shared__ __align__(16) short lds[WPX * UPX * 8];

    const int tid  = threadIdx.x;
    const int lane = tid & 63;
    const int wave = tid >> 6;
    const int q = lane >> 4, n16 = lane & 15;
    const int wx = wave % WX, wy = wave / WX;

    // bijective XCD swizzle (gridDim.x = XT*256, divisible by 8)
    constexpr int NX = XT * 256;
    const int bx = blockIdx.x;
    const int xs = (bx & 7) * (NX >> 3) + (bx >> 3);
    const int xt = xs % XT;
    const int y  = xs / XT;

    int zz = blockIdx.z;
    const short* s0 = srcA;
    int obase = OBASE;
    if (zz >= zsplit) { zz -= zsplit; s0 = srcB; obase += obDelta; }
    const int b  = b0 + zz;

    const int ocWaveBase = blockIdx.y * (16 * NOC * WY) + wy * (16 * NOC);
    const int o16base = ocWaveBase >> 4;
    const int x0 = xt * PXB + wx * PXW;
    const int gxbase = xt * PXB - DIL;

    const int bC = b * CINP;
    const float sc = (MODE == 2) ? 1.f / (xf[b] * (1.f / 3211264.f) + 1e-6f) : 0.f;

    f32x4 acc[G][NOC];
    #pragma unroll
    for (int g = 0; g < G; ++g)
        #pragma unroll
        for (int t = 0; t < NOC; ++t)
            acc[g][t] = {0.f, 0.f, 0.f, 0.f};

    for (int dyi = 0; dyi < 3; ++dyi) {
        const int yy = y + (dyi - 1) * DIL;
        const bool rowok = ((unsigned)yy < 256u);   // block-uniform
        __syncthreads();                            // prev readers done
        if (rowok) {
            const int rowbase = (b * 256 + yy) * 256;
            for (int i = tid; i < WPX * UQ; i += 256) {
                const int pxl = i / UQ;
                const int u   = i - pxl * UQ;
                const int gx  = gxbase + pxl;
                short8 v = {0, 0, 0, 0, 0, 0, 0, 0};
                if ((unsigned)gx < 256u) {
                    const int ic = u * 8;
                    const short* p = (ic < splitK)
                        ? s0 + (size_t)(rowbase + gx) * csA + ic
                        : srcB + (size_t)(rowbase + gx) * csB + (ic - splitK);
                    v = *reinterpret_cast<const short8*>(p);
                    if (MODE == 1) {
                        #pragma unroll
                        for (int c = 0; c < 8; ++c) {
                            const float ka = xf[2 * (bC + ic + c)];
                            const float kb = xf[2 * (bC + ic + c) + 1];
                            float t = s2f(v[c]) * ka + kb;
                            t = fmaxf(t, 0.2f * t);
                            v[c] = f2s(t);
                        }
                    } else if (MODE == 2) {
                        if (ic >= splitK) {
                            #pragma unroll
                            for (int c = 0; c < 8; ++c)
                                v[c] = f2s(s2f(v[c]) * sc);
                        }
                    }
                }
                *reinterpret_cast<short8*>(&lds[(pxl * UPX + u) * 8]) = v;
            }
        }
        __syncthreads();                            // stage visible
        if (!rowok) continue;                       // zero contribution

        #pragma unroll
        for (int dxi = 0; dxi < 3; ++dxi) {
            const int tap = dyi * 3 + dxi;
            #pragma unroll
            for (int cb = 0; cb < CB; ++cb) {
                short8 bfr[G];
                #pragma unroll
                for (int g = 0; g < G; ++g) {
                    const int pxl = wx * PXW + g * 16 + n16 + dxi * DIL;
                    bfr[g] = *reinterpret_cast<const short8*>(
                        &lds[(pxl * UPX + cb * 4 + q) * 8]);
                }
                #pragma unroll
                for (int t = 0; t < NOC; ++t) {
                    short8 a = *reinterpret_cast<const short8*>(
                        wgt + ((((size_t)(o16base + t) * 9 + tap) * CB + cb) * 64 + lane) * 8);
                    #pragma unroll
                    for (int g = 0; g < G; ++g)
                        acc[g][t] = __builtin_amdgcn_mfma_f32_16x16x32_bf16(
                            a, bfr[g], acc[g][t], 0, 0, 0);
                }
            }
        }
    }

    #pragma unroll
    for (int g = 0; g < G; ++g) {
        const size_t px_lin = (size_t)(b * 256 + y) * 256 + x0 + g * 16 + n16;
        #pragma unroll
        for (int t = 0; t < NOC; ++t) {
            const int oc = ocWaveBase + t * 16 + q * 4;
            f32x4 v = acc[g][t];
            if (bias) {
                v.x += bias[oc];     v.y += bias[oc + 1];
                v.z += bias[oc + 2]; v.w += bias[oc + 3];
            }
            ushort4 pk;
            pk.x = (unsigned short)f2s(v.x);
            pk.y = (unsigned short)f2s(v.y);
            pk.z = (unsigned short)f2s(v.z);
            pk.w = (unsigned short)f2s(v.w);
            *reinterpret_cast<ushort4*>(out + px_lin * OSTR + obase + oc) = pk;
        }
    }
}

// ---------------------------------------------------------------------------
// Instance-norm partial sums, NHWC. grid (128 slices, B), block 256.
// ---------------------------------------------------------------------------
__global__ __launch_bounds__(256) void in_stats_nhwc_k(const short* __restrict__ x,
                                                       float* __restrict__ sums,
                                                       int C, int lC)
{
    __shared__ float ls[256], lss[256];
    const int tid = threadIdx.x;
    const int b = blockIdx.y;
    const int c = tid & (C - 1);
    const int sub = tid >> lC;
    const int tpc = 256 >> lC;
    const int px0 = blockIdx.x * 512;
    float s = 0.f, ss = 0.f;
    for (int p = sub; p < 512; p += tpc) {
        float v = s2f(x[(size_t)(b * 65536 + px0 + p) * C + c]);
        s += v; ss += v * v;
    }
    ls[tid] = s; lss[tid] = ss;
    __syncthreads();
    if (tid < C) {
        float s0 = ls[tid], ss0 = lss[tid];
        for (int j = 1; j < tpc; ++j) { s0 += ls[tid + j * C]; ss0 += lss[tid + j * C]; }
        atomicAdd(sums + 2 * (b * C + tid), s0);
        atomicAdd(sums + 2 * (b * C + tid) + 1, ss0);
    }
}

// Emits (ka, kb): apply = x*ka + kb (ka = rsqrt*gamma, kb = beta - m*ka).
__global__ __launch_bounds__(256) void in_finalize_k(const float* __restrict__ sums,
                                                     float* __restrict__ stats,
                                                     const float* __restrict__ gamma,
                                                     const float* __restrict__ beta,
                                                     int lC, int n)
{
    int i = blockIdx.x * 256 + threadIdx.x;
    if (i >= n) return;
    int c = i & ((1 << lC) - 1);
    float m = sums[2 * i] * (1.f / 65536.f);
    float var = sums[2 * i + 1] * (1.f / 65536.f) - m * m;
    if (var < 0.f) var = 0.f;
    float ka = rsqrtf(var + 1e-5f) * gamma[c];
    stats[2 * i] = ka;
    stats[2 * i + 1] = beta[c] - m * ka;
}

// ---------------------------------------------------------------------------
// Separable 7x7 gaussian blur of f1 (A ch 0-63, replicate edges) -> fp16
// planes, group-major: B1[((g*4+b)<<16 | px)*8 + c]. grid (256*8, B).
// ---------------------------------------------------------------------------
__global__ __launch_bounds__(256) void blur_k(const short* __restrict__ A,
                                              short* __restrict__ B1)
{
    __shared__ __align__(16) short raw[484 * 8];    // 22x22 halo, 7.7 KB
    __shared__ __align__(16) float hb[352 * 12];    // 22 rows x 16 cols, 16.9 KB

    const int tid  = threadIdx.x;
    const int tile = blockIdx.x >> 3;
    const int g    = blockIdx.x & 7;
    const int c0   = g * 8;
    const int tx = (tile & 15) << 4;
    const int ty = (tile >> 4) << 4;
    const int b  = blockIdx.y;

    #pragma unroll
    for (int it = 0; it < 2; ++it) {
        int i = tid + it * 256;
        if (i < 484) {
            int y = i / 22, x = i - y * 22;
            int gy = ty + y - 3, gx = tx + x - 3;
            gy = gy < 0 ? 0 : (gy > 255 ? 255 : gy);
            gx = gx < 0 ? 0 : (gx > 255 ? 255 : gx);
            *reinterpret_cast<short8*>(&raw[i * 8]) =
                *reinterpret_cast<const short8*>(
                    &A[(size_t)((b << 16) + (gy << 8) + gx) * 128 + c0]);
        }
    }
    __syncthreads();

    #pragma unroll
    for (int it = 0; it < 2; ++it) {
        int i = tid + it * 256;
        if (i < 352) {                       // 22 rows x 16 core cols
            int r = i >> 4, cc = i & 15;
            float s[8];
            #pragma unroll
            for (int c = 0; c < 8; ++c) s[c] = 0.f;
            #pragma unroll
            for (int j = 0; j < 7; ++j) {
                short8 v = *reinterpret_cast<const short8*>(&raw[(r * 22 + cc + j) * 8]);
                float w = gw(j);
                #pragma unroll
                for (int c = 0; c < 8; ++c) s[c] += w * s2f(v[c]);
            }
            #pragma unroll
            for (int c = 0; c < 8; ++c) hb[i * 12 + c] = s[c];
        }
    }
    __syncthreads();

    const int py = tid >> 4, px = tid & 15;
    float s[8];
    #pragma unroll
    for (int c = 0; c < 8; ++c) s[c] = 0.f;
    #pragma unroll
    for (int j = 0; j < 7; ++j) {
        const float* hp = &hb[((py + j) * 16 + px) * 12];
        float w = gw(j);
        #pragma unroll
        for (int c = 0; c < 8; ++c) s[c] += w * hp[c];
    }
    short8 ov;
    #pragma unroll
    for (int c = 0; c < 8; ++c) ov[c] = f2h(s[c]);
    *reinterpret_cast<short8*>(
        &B1[(size_t)(((g * 4 + b) << 16) + ((ty + py) << 8) + tx + px) * 8]) = ov;
}

// ---------------------------------------------------------------------------
// Local correlation from pre-blurred f1 (fp16 planes) + f2 (A ch 64-127).
// fp16 LDS tiles (row stride 24 cells), double-buffered, v_dot2_f32_f16 SSD.
// Writes UN-normalized lc (e1 staging applies the scale).
// ---------------------------------------------------------------------------
__global__ __launch_bounds__(256, 2) void corr2_k(const short* __restrict__ A,
                                                  const short* __restrict__ B1,
                                                  short* __restrict__ lcPad,
                                                  float* __restrict__ lcsum)
{
    __shared__ __align__(16) short blh[2][22 * 24 * 8];  // 16.5 KB
    __shared__ float red[4];

    const int tid = threadIdx.x;
    const int tx = (blockIdx.x & 15) << 4;
    const int ty = (blockIdx.x >> 4) << 4;
    const int b  = blockIdx.y;
    const int py = tid >> 4, px = tid & 15;

    // Staging descriptors for cells tid and tid+256 (halo +-3).
    int y0 = tid / 22, x0c = tid - y0 * 22;
    int gy0 = ty + y0 - 3, gx0 = tx + x0c - 3;
    const bool ok0 = (gy0 >= 0 && gy0 < 256 && gx0 >= 0 && gx0 < 256);
    gy0 = gy0 < 0 ? 0 : (gy0 > 255 ? 255 : gy0);
    gx0 = gx0 < 0 ? 0 : (gx0 > 255 ? 255 : gx0);
    const int off0 = (gy0 << 8) + gx0;
    const int lc0 = y0 * 24 + x0c;

    const int c1 = tid + 256;
    int y1 = c1 / 22, x1c = c1 - y1 * 22;
    int gy1 = ty + y1 - 3, gx1 = tx + x1c - 3;
    const bool ok1 = (gy1 >= 0 && gy1 < 256 && gx1 >= 0 && gx1 < 256);
    gy1 = gy1 < 0 ? 0 : (gy1 > 255 ? 255 : gy1);
    gx1 = gx1 < 0 ? 0 : (gx1 > 255 ? 255 : gx1);
    const int off1 = (gy1 << 8) + gx1;
    const int lc1 = y1 * 24 + x1c;
    const bool has1 = (c1 < 484);

    const short* f2p = &A[(size_t)((b << 16) + ((ty + py) << 8) + tx + px) * 128 + 64];

    float acc[49];
    #pragma unroll
    for (int k = 0; k < 49; ++k) acc[k] = 0.f;

    for (int g = 0; g < 8; ++g) {
        const size_t plane = (size_t)(g * 4 + b) << 16;
        short* buf = blh[g & 1];

        {
            short8 v = *reinterpret_cast<const short8*>(&B1[(plane + off0) * 8]);
            if (!ok0) v = v ^ v;
            *reinterpret_cast<short8*>(&buf[lc0 * 8]) = v;
            if (has1) {
                short8 w = *reinterpret_cast<const short8*>(&B1[(plane + off1) * 8]);
                if (!ok1) w = w ^ w;
                *reinterpret_cast<short8*>(&buf[lc1 * 8]) = w;
            }
        }

        short8 f2raw = *reinterpret_cast<const short8*>(f2p + g * 8);
        f16x8 f2v;
        #pragma unroll
        for (int c = 0; c < 8; ++c) f2v[c] = (_Float16)s2f(f2raw[c]);

        __syncthreads();

        const short* blp = &buf[(py * 24 + px) * 8];
        #pragma unroll
        for (int i = 0; i < 7; ++i)
            #pragma unroll
            for (int j = 0; j < 7; ++j) {
                f16x8 bv = *reinterpret_cast<const f16x8*>(blp + (i * 24 + j) * 8);
                f16x8 d = f2v - bv;
                float a = acc[i * 7 + j];
#if __has_builtin(__builtin_amdgcn_fdot2)
                a = __builtin_amdgcn_fdot2(__builtin_shufflevector(d, d, 0, 1),
                                           __builtin_shufflevector(d, d, 0, 1), a, false);
                a = __builtin_amdgcn_fdot2(__builtin_shufflevector(d, d, 2, 3),
                                           __builtin_shufflevector(d, d, 2, 3), a, false);
                a = __builtin_amdgcn_fdot2(__builtin_shufflevector(d, d, 4, 5),
                                           __builtin_shufflevector(d, d, 4, 5), a, false);
                a = __builtin_amdgcn_fdot2(__builtin_shufflevector(d, d, 6, 7),
                                           __builtin_shufflevector(d, d, 6, 7), a, false);
#else
                #pragma unroll
                for (int c = 0; c < 8; ++c) {
                    float df = (float)d[c];
                    a += df * df;
                }
#endif
                acc[i * 7 + j] = a;
            }
        __syncthreads();
    }

    const size_t base = (size_t)((b << 16) + ((ty + py) << 8) + tx + px) * 64;
    float tot = 0.f;
    #pragma unroll
    for (int k = 0; k < 49; ++k) {
        float m = acc[k] * (1.f / 64.f);
        lcPad[base + k] = f2s(m);
        tot += m;
    }
    #pragma unroll
    for (int k = 49; k < 64; ++k) lcPad[base + k] = 0;

    for (int o = 32; o; o >>= 1) tot += __shfl_down(tot, o);
    if ((tid & 63) == 0) red[tid >> 6] = tot;
    __syncthreads();
    if (tid == 0) atomicAdd(lcsum + b, red[0] + red[1] + red[2] + red[3]);
}

// ---------------------------------------------------------------------------
// Head conv: applies e3's IN+lrelu (ka,kb table) inline, NHWC bf16 [b,px,16]
// -> NCHW fp32 planes [b*2+oc][px].
// ---------------------------------------------------------------------------
__global__ __launch_bounds__(256) void head_k(const short* __restrict__ e3,
                                              const float* __restrict__ w,
                                              const float* __restrict__ bias,
                                              const float* __restrict__ kst,
                                              float* __restrict__ hd)
{
    int pix = blockIdx.x * 256 + threadIdx.x;
    int b = pix >> 16, rem = pix & 65535;
    int y = rem >> 8, x = rem & 255;
    float ka[16], kb[16];
    #pragma unroll
    for (int ic = 0; ic < 16; ++ic) {
        ka[ic] = kst[2 * (b * 16 + ic)];
        kb[ic] = kst[2 * (b * 16 + ic) + 1];
    }
    float a0 = bias[0], a1 = bias[1];
    #pragma unroll
    for (int tap = 0; tap < 9; ++tap) {
        int yy = y + tap / 3 - 1, xx = x + tap % 3 - 1;
        if ((unsigned)yy >= 256u || (unsigned)xx >= 256u) continue;
        const short* p = e3 + (size_t)((b << 16) + (yy << 8) + xx) * 16;
        #pragma unroll
        for (int ic = 0; ic < 16; ++ic) {
            float v = s2f(p[ic]) * ka[ic] + kb[ic];
            v = fmaxf(v, 0.2f * v);
            a0 += v * w[ic * 9 + tap];
            a1 += v * w[(16 + ic) * 9 + tap];
        }
    }
    hd[(size_t)(b * 2) * 65536 + rem]     = a0;
    hd[(size_t)(b * 2 + 1) * 65536 + rem] = a1;
}

// ---------------------------------------------------------------------------
// Final separable 7-tap gaussian blur (replicate edges), fp32 planes.
// ---------------------------------------------------------------------------
__global__ __launch_bounds__(256) void blur7f_k(const float* __restrict__ in,
                                                float* __restrict__ out)
{
    __shared__ float raw[22 * 22];
    __shared__ float hb[22 * 16];
    const int tid = threadIdx.x;
    const int tx = (blockIdx.x & 15) << 4;
    const int ty = (blockIdx.x >> 4) << 4;
    const size_t ch = ((size_t)blockIdx.y) << 16;
    const int py = tid >> 4, px = tid & 15;

    for (int i = tid; i < 484; i += 256) {
        int y = i / 22, x = i - y * 22;
        int gy = ty + y - 3, gx = tx + x - 3;
        gy = gy < 0 ? 0 : (gy > 255 ? 255 : gy);
        gx = gx < 0 ? 0 : (gx > 255 ? 255 : gx);
        raw[i] = in[ch + (gy << 8) + gx];
    }
    __syncthreads();
    for (int i = tid; i < 352; i += 256) {
        int r = i >> 4, cc = i & 15;
        float s = 0.f;
        #pragma unroll
        for (int j = 0; j < 7; ++j) s += gw(j) * raw[r * 22 + cc + j];
        hb[i] = s;
    }
    __syncthreads();
    float s = 0.f;
    #pragma unroll
    for (int j = 0; j < 7; ++j) s += gw(j) * hb[(py + j) * 16 + px];
    out[ch + ((ty + py) << 8) + tx + px] = s;
}

// ---------------------------------------------------------------------------
extern "C" void kernel_launch(void* const* d_in, const int* in_sizes, int n_in,
                              void* d_out, int out_size, void* d_ws, size_t ws_size,
                              hipStream_t stream)
{
    const float* feat1  = (const float*)d_in[0];
    const float* feat2  = (const float*)d_in[1];
    const float* pre_w  = (const float*)d_in[2];
    const float* pre_b  = (const float*)d_in[3];
    const float* fc1_w  = (const float*)d_in[4];
    const float* fc1_g  = (const float*)d_in[5];
    const float* fc1_be = (const float*)d_in[6];
    const float* fc2_w  = (const float*)d_in[7];
    const float* fc2_b  = (const float*)d_in[8];
    const float* e1_w   = (const float*)d_in[9];
    const float* e1_g   = (const float*)d_in[10];
    const float* e1_be  = (const float*)d_in[11];
    const float* e2_w   = (const float*)d_in[12];
    const float* e2_g   = (const float*)d_in[13];
    const float* e2_be  = (const float*)d_in[14];
    const float* e3_w   = (const float*)d_in[15];
    const float* e3_g   = (const float*)d_in[16];
    const float* e3_be  = (const float*)d_in[17];
    const float* head_w = (const float*)d_in[18];
    const float* head_b = (const float*)d_in[19];
    float* out = (float*)d_out;

    const size_t NEED = 152000000;
    if (ws_size < NEED) return;

    char* ws = (char*)d_ws;
    short* T1      = (short*)(ws);
    short* T2      = (short*)(ws + 33554432);
    short* lcPad   = (short*)(ws);
    short* B1h     = (short*)(ws + 33554432);   // blurred f1, fp16 group-major
    short* featBuf = (short*)(ws + 33554432);
    short* A       = (short*)(ws + 67108864);
    short* FC1o    = (short*)(ws + 83886080);
    short* E1o     = (short*)(ws + 67108864);
    short* E2o     = (short*)(ws + 100663296);
    short* E3o     = (short*)(ws + 117440512);
    float* HD      = (float*)(ws + 125829120);
    short* preW    = (short*)(ws + 150994944);
    short* fc1W    = (short*)(ws + 151068672);
    short* fc2W    = (short*)(ws + 151363584);
    short* e1W     = (short*)(ws + 151511040);
    short* e2W     = (short*)(ws + 151658496);
    short* e3W     = (short*)(ws + 151695360);
    float* sums0   = (float*)(ws + 151704576);
    float* sums1   = (float*)(ws + 151708672);
    float* sums2   = (float*)(ws + 151712768);
    float* sums3   = (float*)(ws + 151716864);
    float* stats0  = (float*)(ws + 151720960);
    float* stats1  = (float*)(ws + 151725056);
    float* stats2  = (float*)(ws + 151729152);
    float* stats3  = (float*)(ws + 151733248);
    float* LS      = (float*)(ws + 151737344);

    hipMemsetAsync(ws + 151704576, 0, 32784, stream);

    // both transposes in one launch (z<4: feat1->T1, z>=4: feat2->T2)
    transpose_k<<<dim3(1024, 8), 256, 0, stream>>>(feat1, feat2, T1, T2);

    repack2_k<<<144, 256, 0, stream>>>(pre_w, preW, 64, 64, 64);
    repack2_k<<<576, 256, 0, stream>>>(fc1_w, fc1W, 128, 128, 128);
    repack2_k<<<288, 256, 0, stream>>>(fc2_w, fc2W, 64, 128, 128);
    repack2_k<<<288, 256, 0, stream>>>(e1_w, e1W, 64, 113, 128);
    repack2_k<<<72, 256, 0, stream>>>(e2_w, e2W, 32, 64, 64);
    repack2_k<<<18, 256, 0, stream>>>(e3_w, e3W, 16, 32, 32);

    // pre conv (cout=64): both feature maps in one z=8 launch
    convmfma_k<1, 64, 2, 2, 2, 4, 0><<<dim3(512, 1, 8), 256, 0, stream>>>(
        T1, T2, 64, 64, 64, preW, pre_b, A, 128, 0, 0, nullptr, 4, 64);

    // blur f1 -> fp16 planes, then local correlation (un-normalized lc)
    blur_k<<<dim3(2048, 4), 256, 0, stream>>>(A, B1h);
    corr2_k<<<dim3(256, 4), 256, 0, stream>>>(A, B1h, lcPad, LS);

    // fc1 (cout=128): batch-phased (FC1o[b] aliases A[b+1]); G=2 -> 1024 blocks
    for (int b = 3; b >= 0; --b)
        convmfma_k<1, 128, 2, 2, 4, 2, 0><<<dim3(1024, 1, 1), 256, 0, stream>>>(
            A, A, 128, 128, 128, fc1W, nullptr, FC1o, 128, 0, b, nullptr, 100, 0);
    in_stats_nhwc_k<<<dim3(128, 4), 256, 0, stream>>>(FC1o, sums0, 128, 7);
    in_finalize_k<<<2, 256, 0, stream>>>(sums0, stats0, fc1_g, fc1_be, 7, 512);

    // fc2 (cout=64): G=2 (17.9KB LDS -> 8 blocks/CU); stages FC1o with
    // IN+lrelu (MODE1, stats0)
    convmfma_k<1, 128, 2, 2, 2, 2, 1><<<dim3(1024, 1, 4), 256, 0, stream>>>(
        FC1o, FC1o, 128, 128, 128, fc2W, fc2_b, featBuf, 64, 0, 0, stats0, 100, 0);

    // e1 (cout=64): G=2; concat(featBuf, lcPad); lc scale in staging (MODE2)
    convmfma_k<1, 128, 2, 2, 2, 2, 2><<<dim3(1024, 1, 4), 256, 0, stream>>>(
        featBuf, lcPad, 64, 64, 64, e1W, nullptr, E1o, 64, 0, 0, LS, 100, 0);
    in_stats_nhwc_k<<<dim3(128, 4), 256, 0, stream>>>(E1o, sums1, 64, 6);
    in_finalize_k<<<1, 256, 0, stream>>>(sums1, stats1, e1_g, e1_be, 6, 256);

    // e2 (cout=32): dil=2, G=2 (9.8KB LDS); stages E1o with IN+lrelu (stats1)
    convmfma_k<2, 64, 2, 2, 1, 2, 1><<<dim3(1024, 1, 4), 256, 0, stream>>>(
        E1o, E1o, 64, 64, 64, e2W, nullptr, E2o, 32, 0, 0, stats1, 100, 0);
    in_stats_nhwc_k<<<dim3(128, 4), 256, 0, stream>>>(E2o, sums2, 32, 5);
    in_finalize_k<<<1, 256, 0, stream>>>(sums2, stats2, e2_g, e2_be, 5, 128);

    // e3 (cout=16): dil=4, G=2/WX=4 (10.9KB LDS, 512 blocks vs 256);
    // stages E2o with IN+lrelu (stats2)
    convmfma_k<4, 32, 4, 1, 1, 2, 1><<<dim3(512, 1, 4), 256, 0, stream>>>(
        E2o, E2o, 32, 32, 32, e3W, nullptr, E3o, 16, 0, 0, stats2, 100, 0);
    in_stats_nhwc_k<<<dim3(128, 4), 256, 0, stream>>>(E3o, sums3, 16, 4);
    in_finalize_k<<<1, 256, 0, stream>>>(sums3, stats3, e3_g, e3_be, 4, 64);

    // head applies e3's IN+lrelu inline
    head_k<<<1024, 256, 0, stream>>>(E3o, head_w, head_b, stats3, HD);
    blur7f_k<<<dim3(256, 8), 256, 0, stream>>>(HD, out);
}